// Round 1
// baseline (590.129 us; speedup 1.0000x reference)
//
#include <hip/hip_runtime.h>
#include <hip/hip_bf16.h>

// Problem constants (match reference)
#define N_NODES 50000
#define N_EDGES 800000
#define IN_C 256
#define HID_C 128
#define OUT_C 64

// ---------------------------------------------------------------------------
// Graph preprocessing kernels
// ---------------------------------------------------------------------------

__global__ __launch_bounds__(256) void init_deg_kernel(int* __restrict__ degi) {
    int i = blockIdx.x * 256 + threadIdx.x;
    if (i < N_NODES) degi[i] = 1;  // self-loop
}

__global__ __launch_bounds__(256) void count_deg_kernel(const int* __restrict__ dst,
                                                        int* __restrict__ degi) {
    int e = blockIdx.x * 256 + threadIdx.x;
    if (e < N_EDGES) atomicAdd(&degi[dst[e]], 1);
}

// Single-block scan: row_ptr (exclusive), cursor copy, dis = rsqrt(deg)
__global__ __launch_bounds__(1024) void scan_kernel(const int* __restrict__ degi,
                                                    int* __restrict__ row_ptr,
                                                    int* __restrict__ cursor,
                                                    float* __restrict__ dis) {
    __shared__ int sums[1024];
    const int T = 1024;
    const int CH = (N_NODES + T - 1) / T;  // 49
    int t = threadIdx.x;
    int b = t * CH;
    int e = b + CH;
    if (e > N_NODES) e = N_NODES;
    int s = 0;
    for (int i = b; i < e; i++) s += degi[i];
    sums[t] = s;
    __syncthreads();
    for (int off = 1; off < T; off <<= 1) {
        int v = sums[t];
        int add = (t >= off) ? sums[t - off] : 0;
        __syncthreads();
        sums[t] = v + add;
        __syncthreads();
    }
    int run = (t == 0) ? 0 : sums[t - 1];
    for (int i = b; i < e; i++) {
        int d = degi[i];
        row_ptr[i] = run;
        cursor[i] = run;
        dis[i] = rsqrtf((float)d);
        run += d;
    }
    if (t == 0) row_ptr[N_NODES] = sums[T - 1];
}

__global__ __launch_bounds__(256) void scatter_kernel(const int* __restrict__ src,
                                                      const int* __restrict__ dst,
                                                      const float* __restrict__ dis,
                                                      int* __restrict__ cursor,
                                                      int* __restrict__ csr_src,
                                                      float* __restrict__ csr_norm) {
    int i = blockIdx.x * 256 + threadIdx.x;
    if (i >= N_EDGES + N_NODES) return;
    int s, d;
    if (i < N_EDGES) {
        s = src[i];
        d = dst[i];
    } else {
        s = d = i - N_EDGES;
    }
    float w = dis[s] * dis[d];
    int slot = atomicAdd(&cursor[d], 1);
    csr_src[slot] = s;
    csr_norm[slot] = w;
}

// ---------------------------------------------------------------------------
// fp32 tiled GEMM: C[M][N] = A[M][K] @ W[K][N] (+ bias)
// BM=64, BK=64, 256 threads, per-thread tile TM x 8
// ---------------------------------------------------------------------------

template <int K, int N, bool BIAS>
__global__ __launch_bounds__(256) void gemm_kernel(const float* __restrict__ A,
                                                   const float* __restrict__ W,
                                                   const float* __restrict__ bias,
                                                   float* __restrict__ C, int M) {
    constexpr int BM = 64;
    constexpr int BK = 64;
    constexpr int TN = 8;
    constexpr int TX = N / TN;     // 16 (N=128) or 8 (N=64)
    constexpr int TY = 256 / TX;   // 16 or 32
    constexpr int TM = BM / TY;    // 4 or 2

    __shared__ float As[BK][BM + 1];   // transposed A tile, +1 pad
    __shared__ float Ws[BK][N + 4];    // row-major W tile, 16B-aligned rows

    const int tid = threadIdx.x;
    const int tx = tid % TX;
    const int ty = tid / TX;
    const int row0 = blockIdx.x * BM;

    float acc[TM][TN];
#pragma unroll
    for (int i = 0; i < TM; i++)
#pragma unroll
        for (int j = 0; j < TN; j++) acc[i][j] = 0.f;

    for (int kk = 0; kk < K; kk += BK) {
        // Load A tile (BM x BK) transposed into LDS
#pragma unroll
        for (int l = 0; l < 4; l++) {
            int slot = tid + l * 256;      // 0..1023 float4 slots
            int r = slot / (BK / 4);       // row 0..63
            int c4 = slot % (BK / 4);      // col-group 0..15
            float4 v = make_float4(0.f, 0.f, 0.f, 0.f);
            int grow = row0 + r;
            if (grow < M) v = *(const float4*)&A[(size_t)grow * K + kk + c4 * 4];
            As[c4 * 4 + 0][r] = v.x;
            As[c4 * 4 + 1][r] = v.y;
            As[c4 * 4 + 2][r] = v.z;
            As[c4 * 4 + 3][r] = v.w;
        }
        // Load W tile (BK x N)
        constexpr int WL = (BK * N / 4) / 256;
#pragma unroll
        for (int l = 0; l < WL; l++) {
            int slot = tid + l * 256;
            int r = slot / (N / 4);
            int c4 = slot % (N / 4);
            float4 v = *(const float4*)&W[(size_t)(kk + r) * N + c4 * 4];
            *(float4*)&Ws[r][c4 * 4] = v;
        }
        __syncthreads();

#pragma unroll 8
        for (int k = 0; k < BK; k++) {
            float a[TM], w[TN];
#pragma unroll
            for (int i = 0; i < TM; i++) a[i] = As[k][ty * TM + i];
#pragma unroll
            for (int j = 0; j < TN; j++) w[j] = Ws[k][tx * TN + j];
#pragma unroll
            for (int i = 0; i < TM; i++)
#pragma unroll
                for (int j = 0; j < TN; j++) acc[i][j] += a[i] * w[j];
        }
        __syncthreads();
    }

#pragma unroll
    for (int i = 0; i < TM; i++) {
        int grow = row0 + ty * TM + i;
        if (grow >= M) continue;
#pragma unroll
        for (int j = 0; j < TN; j += 4) {
            float4 v;
            v.x = acc[i][j + 0];
            v.y = acc[i][j + 1];
            v.z = acc[i][j + 2];
            v.w = acc[i][j + 3];
            if (BIAS) {
                v.x += bias[tx * TN + j + 0];
                v.y += bias[tx * TN + j + 1];
                v.z += bias[tx * TN + j + 2];
                v.w += bias[tx * TN + j + 3];
            }
            *(float4*)&C[(size_t)grow * N + tx * TN + j] = v;
        }
    }
}

// ---------------------------------------------------------------------------
// CSR aggregation: out[n] = relu(sum_e norm[e]*g[src[e]] + bias), one wave/node
// ---------------------------------------------------------------------------

__global__ __launch_bounds__(256) void aggregate_kernel(const float* __restrict__ g,
                                                        const int* __restrict__ row_ptr,
                                                        const int* __restrict__ csr_src,
                                                        const float* __restrict__ csr_norm,
                                                        const float* __restrict__ bias,
                                                        float* __restrict__ out) {
    int wid = threadIdx.x >> 6;
    int lane = threadIdx.x & 63;
    int node = blockIdx.x * 4 + wid;
    if (node >= N_NODES) return;

    int s0 = row_ptr[node];
    int s1 = row_ptr[node + 1];

    float ax = 0.f, ay = 0.f;
    int e = s0;
    for (; e + 3 < s1; e += 4) {
        int i0 = csr_src[e + 0];
        int i1 = csr_src[e + 1];
        int i2 = csr_src[e + 2];
        int i3 = csr_src[e + 3];
        float w0 = csr_norm[e + 0];
        float w1 = csr_norm[e + 1];
        float w2 = csr_norm[e + 2];
        float w3 = csr_norm[e + 3];
        float2 v0 = *(const float2*)&g[(size_t)i0 * HID_C + lane * 2];
        float2 v1 = *(const float2*)&g[(size_t)i1 * HID_C + lane * 2];
        float2 v2 = *(const float2*)&g[(size_t)i2 * HID_C + lane * 2];
        float2 v3 = *(const float2*)&g[(size_t)i3 * HID_C + lane * 2];
        ax += w0 * v0.x + w1 * v1.x + w2 * v2.x + w3 * v3.x;
        ay += w0 * v0.y + w1 * v1.y + w2 * v2.y + w3 * v3.y;
    }
    for (; e < s1; e++) {
        int i0 = csr_src[e];
        float w0 = csr_norm[e];
        float2 v0 = *(const float2*)&g[(size_t)i0 * HID_C + lane * 2];
        ax += w0 * v0.x;
        ay += w0 * v0.y;
    }
    float2 bb = *(const float2*)&bias[lane * 2];
    float2 o;
    o.x = fmaxf(ax + bb.x, 0.f);
    o.y = fmaxf(ay + bb.y, 0.f);
    *(float2*)&out[(size_t)node * HID_C + lane * 2] = o;
}

// ---------------------------------------------------------------------------
// Launch
// ---------------------------------------------------------------------------

extern "C" void kernel_launch(void* const* d_in, const int* in_sizes, int n_in,
                              void* d_out, int out_size, void* d_ws, size_t ws_size,
                              hipStream_t stream) {
    const float* x       = (const float*)d_in[0];
    const int*   eidx    = (const int*)d_in[1];
    const float* proj_W  = (const float*)d_in[2];
    const float* proj_b  = (const float*)d_in[3];
    const float* conv_W0 = (const float*)d_in[4];
    const float* conv_b0 = (const float*)d_in[5];
    const float* conv_W1 = (const float*)d_in[6];
    const float* conv_b1 = (const float*)d_in[7];
    const float* conv_W2 = (const float*)d_in[8];
    const float* conv_b2 = (const float*)d_in[9];
    const float* out_W   = (const float*)d_in[10];
    const float* out_b   = (const float*)d_in[11];
    float* out = (float*)d_out;

    const int* src = eidx;
    const int* dst = eidx + N_EDGES;

    // Workspace carve (256B aligned)
    char* ws = (char*)d_ws;
    size_t off = 0;
    auto carve = [&](size_t bytes) {
        void* p = ws + off;
        off += (bytes + 255) & ~(size_t)255;
        return p;
    };
    int*   degi     = (int*)carve(N_NODES * sizeof(int));
    int*   row_ptr  = (int*)carve((N_NODES + 1) * sizeof(int));
    int*   cursor   = (int*)carve(N_NODES * sizeof(int));
    int*   csr_src  = (int*)carve((size_t)(N_EDGES + N_NODES) * sizeof(int));
    float* csr_norm = (float*)carve((size_t)(N_EDGES + N_NODES) * sizeof(float));
    float* dis      = (float*)carve(N_NODES * sizeof(float));
    float* hA       = (float*)carve((size_t)N_NODES * HID_C * sizeof(float));
    float* hB       = (float*)carve((size_t)N_NODES * HID_C * sizeof(float));

    // Graph preprocessing
    init_deg_kernel<<<(N_NODES + 255) / 256, 256, 0, stream>>>(degi);
    count_deg_kernel<<<(N_EDGES + 255) / 256, 256, 0, stream>>>(dst, degi);
    scan_kernel<<<1, 1024, 0, stream>>>(degi, row_ptr, cursor, dis);
    scatter_kernel<<<(N_EDGES + N_NODES + 255) / 256, 256, 0, stream>>>(
        src, dst, dis, cursor, csr_src, csr_norm);

    const int gemm_grid = (N_NODES + 63) / 64;

    // Projection: hA = x @ proj_W + proj_b
    gemm_kernel<IN_C, HID_C, true><<<gemm_grid, 256, 0, stream>>>(
        x, proj_W, proj_b, hA, N_NODES);

    // 3 GCN layers
    const float* Ws_[3] = {conv_W0, conv_W1, conv_W2};
    const float* bs_[3] = {conv_b0, conv_b1, conv_b2};
    for (int l = 0; l < 3; l++) {
        gemm_kernel<HID_C, HID_C, false><<<gemm_grid, 256, 0, stream>>>(
            hA, Ws_[l], nullptr, hB, N_NODES);
        aggregate_kernel<<<(N_NODES + 3) / 4, 256, 0, stream>>>(
            hB, row_ptr, csr_src, csr_norm, bs_[l], hA);
    }

    // Output: out = hA @ out_W + out_b
    gemm_kernel<HID_C, OUT_C, true><<<gemm_grid, 256, 0, stream>>>(
        hA, out_W, out_b, out, N_NODES);
}

// Round 2
// 477.084 us; speedup vs baseline: 1.2369x; 1.2369x over previous
//
#include <hip/hip_runtime.h>
#include <hip/hip_bf16.h>

// Problem constants (match reference)
#define N_NODES 50000
#define N_EDGES 800000
#define IN_C 256
#define HID_C 128
#define OUT_C 64

#define NB_SCAN ((N_NODES + 255) / 256)   // 196 blocks of 256 nodes

// ---------------------------------------------------------------------------
// Graph preprocessing kernels
// ---------------------------------------------------------------------------

__global__ __launch_bounds__(256) void init_deg_kernel(int* __restrict__ degi) {
    int i = blockIdx.x * 256 + threadIdx.x;
    if (i < N_NODES) degi[i] = 1;  // self-loop
}

__global__ __launch_bounds__(256) void count_deg_kernel(const int* __restrict__ dst,
                                                        int* __restrict__ degi) {
    int e = blockIdx.x * 256 + threadIdx.x;
    if (e < N_EDGES) atomicAdd(&degi[dst[e]], 1);
}

// Multi-block scan, step 1: per-block degree sums
__global__ __launch_bounds__(256) void deg_partial_kernel(const int* __restrict__ degi,
                                                          int* __restrict__ partials) {
    __shared__ int s[256];
    int t = threadIdx.x;
    int i = blockIdx.x * 256 + t;
    s[t] = (i < N_NODES) ? degi[i] : 0;
    __syncthreads();
#pragma unroll
    for (int off = 128; off > 0; off >>= 1) {
        if (t < off) s[t] += s[t + off];
        __syncthreads();
    }
    if (t == 0) partials[blockIdx.x] = s[0];
}

// Step 2: scan the 196 partials in one small block; also writes row_ptr[N]
__global__ __launch_bounds__(256) void scan_partials_kernel(const int* __restrict__ partials,
                                                            int* __restrict__ partial_off,
                                                            int* __restrict__ row_ptr) {
    __shared__ int s[256];
    int t = threadIdx.x;
    s[t] = (t < NB_SCAN) ? partials[t] : 0;
    __syncthreads();
#pragma unroll
    for (int off = 1; off < 256; off <<= 1) {
        int x = s[t];
        int add = (t >= off) ? s[t - off] : 0;
        __syncthreads();
        s[t] = x + add;
        __syncthreads();
    }
    if (t < NB_SCAN) partial_off[t] = (t == 0) ? 0 : s[t - 1];
    if (t == 255) row_ptr[N_NODES] = s[255];
}

// Step 3: per-block exclusive scan + global offset -> row_ptr, cursor, dis
__global__ __launch_bounds__(256) void scan_final_kernel(const int* __restrict__ degi,
                                                         const int* __restrict__ partial_off,
                                                         int* __restrict__ row_ptr,
                                                         int* __restrict__ cursor,
                                                         float* __restrict__ dis) {
    __shared__ int s[256];
    int t = threadIdx.x;
    int i = blockIdx.x * 256 + t;
    int d = (i < N_NODES) ? degi[i] : 0;
    s[t] = d;
    __syncthreads();
#pragma unroll
    for (int off = 1; off < 256; off <<= 1) {
        int x = s[t];
        int add = (t >= off) ? s[t - off] : 0;
        __syncthreads();
        s[t] = x + add;
        __syncthreads();
    }
    if (i < N_NODES) {
        int excl = partial_off[blockIdx.x] + s[t] - d;
        row_ptr[i] = excl;
        cursor[i] = excl;
        dis[i] = rsqrtf((float)d);
    }
}

__global__ __launch_bounds__(256) void scatter_kernel(const int* __restrict__ src,
                                                      const int* __restrict__ dst,
                                                      const float* __restrict__ dis,
                                                      int* __restrict__ cursor,
                                                      int* __restrict__ csr_src,
                                                      float* __restrict__ csr_norm) {
    int i = blockIdx.x * 256 + threadIdx.x;
    if (i >= N_EDGES + N_NODES) return;
    int s, d;
    if (i < N_EDGES) {
        s = src[i];
        d = dst[i];
    } else {
        s = d = i - N_EDGES;
    }
    float w = dis[s] * dis[d];
    int slot = atomicAdd(&cursor[d], 1);
    csr_src[slot] = s;
    csr_norm[slot] = w;
}

// ---------------------------------------------------------------------------
// fp32 tiled GEMM: C[M][N] = A[M][K] @ W[K][N] (+ bias)
// BM=64, BK=64, 256 threads, per-thread tile TM x 8
// ---------------------------------------------------------------------------

template <int K, int N, bool BIAS>
__global__ __launch_bounds__(256) void gemm_kernel(const float* __restrict__ A,
                                                   const float* __restrict__ W,
                                                   const float* __restrict__ bias,
                                                   float* __restrict__ C, int M) {
    constexpr int BM = 64;
    constexpr int BK = 64;
    constexpr int TN = 8;
    constexpr int TX = N / TN;     // 16 (N=128) or 8 (N=64)
    constexpr int TY = 256 / TX;   // 16 or 32
    constexpr int TM = BM / TY;    // 4 or 2

    __shared__ float As[BK][BM + 1];   // transposed A tile, +1 pad
    __shared__ float Ws[BK][N + 4];    // row-major W tile

    const int tid = threadIdx.x;
    const int tx = tid % TX;
    const int ty = tid / TX;
    const int row0 = blockIdx.x * BM;

    float acc[TM][TN];
#pragma unroll
    for (int i = 0; i < TM; i++)
#pragma unroll
        for (int j = 0; j < TN; j++) acc[i][j] = 0.f;

    for (int kk = 0; kk < K; kk += BK) {
        // Load A tile (BM x BK) transposed into LDS
#pragma unroll
        for (int l = 0; l < 4; l++) {
            int slot = tid + l * 256;      // 0..1023 float4 slots
            int r = slot / (BK / 4);       // row 0..63
            int c4 = slot % (BK / 4);      // col-group 0..15
            float4 v = make_float4(0.f, 0.f, 0.f, 0.f);
            int grow = row0 + r;
            if (grow < M) v = *(const float4*)&A[(size_t)grow * K + kk + c4 * 4];
            As[c4 * 4 + 0][r] = v.x;
            As[c4 * 4 + 1][r] = v.y;
            As[c4 * 4 + 2][r] = v.z;
            As[c4 * 4 + 3][r] = v.w;
        }
        // Load W tile (BK x N)
        constexpr int WL = (BK * N / 4) / 256;
#pragma unroll
        for (int l = 0; l < WL; l++) {
            int slot = tid + l * 256;
            int r = slot / (N / 4);
            int c4 = slot % (N / 4);
            float4 v = *(const float4*)&W[(size_t)(kk + r) * N + c4 * 4];
            *(float4*)&Ws[r][c4 * 4] = v;
        }
        __syncthreads();

#pragma unroll 8
        for (int k = 0; k < BK; k++) {
            float a[TM], w[TN];
#pragma unroll
            for (int i = 0; i < TM; i++) a[i] = As[k][ty * TM + i];
#pragma unroll
            for (int j = 0; j < TN; j++) w[j] = Ws[k][tx * TN + j];
#pragma unroll
            for (int i = 0; i < TM; i++)
#pragma unroll
                for (int j = 0; j < TN; j++) acc[i][j] += a[i] * w[j];
        }
        __syncthreads();
    }

#pragma unroll
    for (int i = 0; i < TM; i++) {
        int grow = row0 + ty * TM + i;
        if (grow >= M) continue;
#pragma unroll
        for (int j = 0; j < TN; j += 4) {
            float4 v;
            v.x = acc[i][j + 0];
            v.y = acc[i][j + 1];
            v.z = acc[i][j + 2];
            v.w = acc[i][j + 3];
            if (BIAS) {
                v.x += bias[tx * TN + j + 0];
                v.y += bias[tx * TN + j + 1];
                v.z += bias[tx * TN + j + 2];
                v.w += bias[tx * TN + j + 3];
            }
            *(float4*)&C[(size_t)grow * N + tx * TN + j] = v;
        }
    }
}

// ---------------------------------------------------------------------------
// CSR aggregation: out[n] = relu(sum_e norm[e]*g[src[e]] + bias), one wave/node
// ---------------------------------------------------------------------------

__global__ __launch_bounds__(256) void aggregate_kernel(const float* __restrict__ g,
                                                        const int* __restrict__ row_ptr,
                                                        const int* __restrict__ csr_src,
                                                        const float* __restrict__ csr_norm,
                                                        const float* __restrict__ bias,
                                                        float* __restrict__ out) {
    int wid = threadIdx.x >> 6;
    int lane = threadIdx.x & 63;
    int node = blockIdx.x * 4 + wid;
    if (node >= N_NODES) return;

    int s0 = row_ptr[node];
    int s1 = row_ptr[node + 1];

    float ax = 0.f, ay = 0.f;
    int e = s0;
    for (; e + 3 < s1; e += 4) {
        int i0 = csr_src[e + 0];
        int i1 = csr_src[e + 1];
        int i2 = csr_src[e + 2];
        int i3 = csr_src[e + 3];
        float w0 = csr_norm[e + 0];
        float w1 = csr_norm[e + 1];
        float w2 = csr_norm[e + 2];
        float w3 = csr_norm[e + 3];
        float2 v0 = *(const float2*)&g[(size_t)i0 * HID_C + lane * 2];
        float2 v1 = *(const float2*)&g[(size_t)i1 * HID_C + lane * 2];
        float2 v2 = *(const float2*)&g[(size_t)i2 * HID_C + lane * 2];
        float2 v3 = *(const float2*)&g[(size_t)i3 * HID_C + lane * 2];
        ax += w0 * v0.x + w1 * v1.x + w2 * v2.x + w3 * v3.x;
        ay += w0 * v0.y + w1 * v1.y + w2 * v2.y + w3 * v3.y;
    }
    for (; e < s1; e++) {
        int i0 = csr_src[e];
        float w0 = csr_norm[e];
        float2 v0 = *(const float2*)&g[(size_t)i0 * HID_C + lane * 2];
        ax += w0 * v0.x;
        ay += w0 * v0.y;
    }
    float2 bb = *(const float2*)&bias[lane * 2];
    float2 o;
    o.x = fmaxf(ax + bb.x, 0.f);
    o.y = fmaxf(ay + bb.y, 0.f);
    *(float2*)&out[(size_t)node * HID_C + lane * 2] = o;
}

// ---------------------------------------------------------------------------
// Launch
// ---------------------------------------------------------------------------

extern "C" void kernel_launch(void* const* d_in, const int* in_sizes, int n_in,
                              void* d_out, int out_size, void* d_ws, size_t ws_size,
                              hipStream_t stream) {
    const float* x       = (const float*)d_in[0];
    const int*   eidx    = (const int*)d_in[1];
    const float* proj_W  = (const float*)d_in[2];
    const float* proj_b  = (const float*)d_in[3];
    const float* conv_W0 = (const float*)d_in[4];
    const float* conv_b0 = (const float*)d_in[5];
    const float* conv_W1 = (const float*)d_in[6];
    const float* conv_b1 = (const float*)d_in[7];
    const float* conv_W2 = (const float*)d_in[8];
    const float* conv_b2 = (const float*)d_in[9];
    const float* out_W   = (const float*)d_in[10];
    const float* out_b   = (const float*)d_in[11];
    float* out = (float*)d_out;

    const int* src = eidx;
    const int* dst = eidx + N_EDGES;

    // Workspace carve (256B aligned)
    char* ws = (char*)d_ws;
    size_t off = 0;
    auto carve = [&](size_t bytes) {
        void* p = ws + off;
        off += (bytes + 255) & ~(size_t)255;
        return p;
    };
    int*   degi     = (int*)carve(N_NODES * sizeof(int));
    int*   row_ptr  = (int*)carve((N_NODES + 1) * sizeof(int));
    int*   cursor   = (int*)carve(N_NODES * sizeof(int));
    int*   csr_src  = (int*)carve((size_t)(N_EDGES + N_NODES) * sizeof(int));
    float* csr_norm = (float*)carve((size_t)(N_EDGES + N_NODES) * sizeof(float));
    float* dis      = (float*)carve(N_NODES * sizeof(float));
    int*   partials = (int*)carve(NB_SCAN * sizeof(int));
    int*   poff     = (int*)carve(NB_SCAN * sizeof(int));
    float* hA       = (float*)carve((size_t)N_NODES * HID_C * sizeof(float));
    float* hB       = (float*)carve((size_t)N_NODES * HID_C * sizeof(float));

    // Graph preprocessing
    init_deg_kernel<<<NB_SCAN, 256, 0, stream>>>(degi);
    count_deg_kernel<<<(N_EDGES + 255) / 256, 256, 0, stream>>>(dst, degi);
    deg_partial_kernel<<<NB_SCAN, 256, 0, stream>>>(degi, partials);
    scan_partials_kernel<<<1, 256, 0, stream>>>(partials, poff, row_ptr);
    scan_final_kernel<<<NB_SCAN, 256, 0, stream>>>(degi, poff, row_ptr, cursor, dis);
    scatter_kernel<<<(N_EDGES + N_NODES + 255) / 256, 256, 0, stream>>>(
        src, dst, dis, cursor, csr_src, csr_norm);

    const int gemm_grid = (N_NODES + 63) / 64;

    // Projection: hA = x @ proj_W + proj_b
    gemm_kernel<IN_C, HID_C, true><<<gemm_grid, 256, 0, stream>>>(
        x, proj_W, proj_b, hA, N_NODES);

    // 3 GCN layers
    const float* Ws_[3] = {conv_W0, conv_W1, conv_W2};
    const float* bs_[3] = {conv_b0, conv_b1, conv_b2};
    for (int l = 0; l < 3; l++) {
        gemm_kernel<HID_C, HID_C, false><<<gemm_grid, 256, 0, stream>>>(
            hA, Ws_[l], nullptr, hB, N_NODES);
        aggregate_kernel<<<(N_NODES + 3) / 4, 256, 0, stream>>>(
            hB, row_ptr, csr_src, csr_norm, bs_[l], hA);
    }

    // Output: out = hA @ out_W + out_b
    gemm_kernel<HID_C, OUT_C, true><<<gemm_grid, 256, 0, stream>>>(
        hA, out_W, out_b, out, N_NODES);
}

// Round 3
// 387.653 us; speedup vs baseline: 1.5223x; 1.2307x over previous
//
#include <hip/hip_runtime.h>
#include <hip/hip_bf16.h>

// Problem constants (match reference)
#define N_NODES 50000
#define N_EDGES 800000
#define IN_C 256
#define HID_C 128
#define OUT_C 64

#define NB_SCAN ((N_NODES + 255) / 256)   // 196 blocks of 256 nodes

typedef __attribute__((ext_vector_type(8))) short bf16x8;
typedef __attribute__((ext_vector_type(4))) float f32x4;

__device__ __forceinline__ ushort f2bf(float f) {
    uint u = __float_as_uint(f);
    u += 0x7fff + ((u >> 16) & 1);   // round-to-nearest-even
    return (ushort)(u >> 16);
}
__device__ __forceinline__ float bf2f(ushort h) {
    return __uint_as_float(((uint)h) << 16);
}

// ---------------------------------------------------------------------------
// Graph preprocessing
// ---------------------------------------------------------------------------

__global__ __launch_bounds__(256) void init_deg_kernel(int* __restrict__ degi) {
    int i = blockIdx.x * 256 + threadIdx.x;
    if (i < N_NODES) degi[i] = 1;  // self-loop
}

__global__ __launch_bounds__(256) void count_deg_kernel(const int* __restrict__ dst,
                                                        int* __restrict__ degi) {
    int e = blockIdx.x * 256 + threadIdx.x;
    if (e < N_EDGES) atomicAdd(&degi[dst[e]], 1);
}

__global__ __launch_bounds__(256) void deg_partial_kernel(const int* __restrict__ degi,
                                                          int* __restrict__ partials) {
    __shared__ int s[256];
    int t = threadIdx.x;
    int i = blockIdx.x * 256 + t;
    s[t] = (i < N_NODES) ? degi[i] : 0;
    __syncthreads();
#pragma unroll
    for (int off = 128; off > 0; off >>= 1) {
        if (t < off) s[t] += s[t + off];
        __syncthreads();
    }
    if (t == 0) partials[blockIdx.x] = s[0];
}

__global__ __launch_bounds__(256) void scan_partials_kernel(const int* __restrict__ partials,
                                                            int* __restrict__ partial_off,
                                                            int* __restrict__ row_ptr) {
    __shared__ int s[256];
    int t = threadIdx.x;
    s[t] = (t < NB_SCAN) ? partials[t] : 0;
    __syncthreads();
#pragma unroll
    for (int off = 1; off < 256; off <<= 1) {
        int x = s[t];
        int add = (t >= off) ? s[t - off] : 0;
        __syncthreads();
        s[t] = x + add;
        __syncthreads();
    }
    if (t < NB_SCAN) partial_off[t] = (t == 0) ? 0 : s[t - 1];
    if (t == 255) row_ptr[N_NODES] = s[255];
}

__global__ __launch_bounds__(256) void scan_final_kernel(const int* __restrict__ degi,
                                                         const int* __restrict__ partial_off,
                                                         int* __restrict__ row_ptr,
                                                         int* __restrict__ cursor,
                                                         float* __restrict__ dis) {
    __shared__ int s[256];
    int t = threadIdx.x;
    int i = blockIdx.x * 256 + t;
    int d = (i < N_NODES) ? degi[i] : 0;
    s[t] = d;
    __syncthreads();
#pragma unroll
    for (int off = 1; off < 256; off <<= 1) {
        int x = s[t];
        int add = (t >= off) ? s[t - off] : 0;
        __syncthreads();
        s[t] = x + add;
        __syncthreads();
    }
    if (i < N_NODES) {
        int excl = partial_off[blockIdx.x] + s[t] - d;
        row_ptr[i] = excl;
        cursor[i] = excl;
        dis[i] = rsqrtf((float)d);
    }
}

// One 8B scatter per edge: {src, norm}
__global__ __launch_bounds__(256) void scatter_kernel(const int* __restrict__ src,
                                                      const int* __restrict__ dst,
                                                      const float* __restrict__ dis,
                                                      int* __restrict__ cursor,
                                                      int2* __restrict__ csr) {
    int i = blockIdx.x * 256 + threadIdx.x;
    if (i >= N_EDGES + N_NODES) return;
    int s, d;
    if (i < N_EDGES) {
        s = src[i];
        d = dst[i];
    } else {
        s = d = i - N_EDGES;
    }
    float w = dis[s] * dis[d];
    int slot = atomicAdd(&cursor[d], 1);
    int2 ent;
    ent.x = s;
    ent.y = __float_as_int(w);
    csr[slot] = ent;
}

// ---------------------------------------------------------------------------
// Weight packing: W[K][N] fp32 -> fragment-ordered bf16 hi/lo
// layout: Pk[kt][ct][lane][j], element = W[kt*32 + (lane>>4)*8 + j][ct*16 + (lane&15)]
// launch: <<<(K/32)*(N/16), 64>>>
// ---------------------------------------------------------------------------

__global__ __launch_bounds__(64) void pack_w_kernel(const float* __restrict__ W,
                                                    ushort* __restrict__ Ph,
                                                    ushort* __restrict__ Pl,
                                                    int K, int N) {
    int lane = threadIdx.x;
    int CT = N / 16;
    int ct = blockIdx.x % CT;
    int kt = blockIdx.x / CT;
    int lr = lane & 15, lg = lane >> 4;
    size_t base = ((size_t)blockIdx.x * 64 + lane) * 8;
#pragma unroll
    for (int j = 0; j < 8; j++) {
        float w = W[(size_t)(kt * 32 + lg * 8 + j) * N + ct * 16 + lr];
        ushort h = f2bf(w);
        ushort lo = f2bf(w - bf2f(h));
        Ph[base + j] = h;
        Pl[base + j] = lo;
    }
}

// ---------------------------------------------------------------------------
// LDS-free MFMA GEMM with 3-term bf16 split.
// C[M][N] = A[M][K] @ W[K][N] (+bias). Wave owns 32 rows x N cols.
// Block = 4 waves = 128 rows. A fragments direct from global; B from packed W.
// OUT_MODE: 0 = fp32 + bias, 1 = bf16 hi/lo + bias, 2 = fp32 no bias
// ---------------------------------------------------------------------------

template <int K, int N, int OUT_MODE, bool AF32>
__global__ __launch_bounds__(256) void gemm_mfma_kernel(
    const float* __restrict__ Af, const ushort* __restrict__ Ahi,
    const ushort* __restrict__ Alo, const ushort* __restrict__ Wph,
    const ushort* __restrict__ Wpl, const float* __restrict__ bias,
    float* __restrict__ Cf, ushort* __restrict__ CHi, ushort* __restrict__ CLo,
    int M) {
    constexpr int CT = N / 16;
    constexpr int KT = K / 32;

    const int wid = threadIdx.x >> 6;
    const int lane = threadIdx.x & 63;
    const int lr = lane & 15;   // row within 16-tile (A), col within tile (B/D)
    const int lg = lane >> 4;   // k-group / row-group
    const int row_base = blockIdx.x * 128 + wid * 32;

    f32x4 acc[2][CT];
#pragma unroll
    for (int rt = 0; rt < 2; rt++)
#pragma unroll
        for (int ct = 0; ct < CT; ct++) acc[rt][ct] = (f32x4){0.f, 0.f, 0.f, 0.f};

    for (int kt = 0; kt < KT; kt++) {
        const int kof = kt * 32 + lg * 8;
        bf16x8 ah[2], al[2];
#pragma unroll
        for (int rt = 0; rt < 2; rt++) {
            int r = row_base + rt * 16 + lr;
            if (r >= M) r = M - 1;  // clamp; result discarded on store
            if (AF32) {
                const float* ap = &Af[(size_t)r * K + kof];
                float4 v0 = *(const float4*)ap;
                float4 v1 = *(const float4*)(ap + 4);
                float av[8] = {v0.x, v0.y, v0.z, v0.w, v1.x, v1.y, v1.z, v1.w};
#pragma unroll
                for (int j = 0; j < 8; j++) {
                    ushort h = f2bf(av[j]);
                    ushort lo = f2bf(av[j] - bf2f(h));
                    ah[rt][j] = (short)h;
                    al[rt][j] = (short)lo;
                }
            } else {
                ah[rt] = *(const bf16x8*)&Ahi[(size_t)r * K + kof];
                al[rt] = *(const bf16x8*)&Alo[(size_t)r * K + kof];
            }
        }
        const ushort* bh = &Wph[(size_t)kt * CT * 512 + (size_t)lane * 8];
        const ushort* bl = &Wpl[(size_t)kt * CT * 512 + (size_t)lane * 8];
#pragma unroll
        for (int ct = 0; ct < CT; ct++) {
            bf16x8 bhv = *(const bf16x8*)(bh + ct * 512);
            bf16x8 blv = *(const bf16x8*)(bl + ct * 512);
#pragma unroll
            for (int rt = 0; rt < 2; rt++) {
                acc[rt][ct] = __builtin_amdgcn_mfma_f32_16x16x32_bf16(ah[rt], bhv, acc[rt][ct], 0, 0, 0);
                acc[rt][ct] = __builtin_amdgcn_mfma_f32_16x16x32_bf16(al[rt], bhv, acc[rt][ct], 0, 0, 0);
                acc[rt][ct] = __builtin_amdgcn_mfma_f32_16x16x32_bf16(ah[rt], blv, acc[rt][ct], 0, 0, 0);
            }
        }
    }

    // Epilogue: D[row][col], row = rt*16 + lg*4 + j, col = ct*16 + lr
#pragma unroll
    for (int rt = 0; rt < 2; rt++)
#pragma unroll
        for (int ct = 0; ct < CT; ct++)
#pragma unroll
            for (int j = 0; j < 4; j++) {
                int r = row_base + rt * 16 + lg * 4 + j;
                if (r >= M) continue;
                int c = ct * 16 + lr;
                float v = acc[rt][ct][j];
                if (OUT_MODE != 2) v += bias[c];
                if (OUT_MODE == 1) {
                    ushort h = f2bf(v);
                    ushort lo = f2bf(v - bf2f(h));
                    CHi[(size_t)r * N + c] = h;
                    CLo[(size_t)r * N + c] = lo;
                } else {
                    Cf[(size_t)r * N + c] = v;
                }
            }
}

// ---------------------------------------------------------------------------
// CSR aggregation: out = relu(sum norm*g[src] + bias), one wave/node.
// Writes bf16 hi/lo for the next layer's GEMM.
// ---------------------------------------------------------------------------

__global__ __launch_bounds__(256) void aggregate_kernel(const float* __restrict__ g,
                                                        const int* __restrict__ row_ptr,
                                                        const int2* __restrict__ csr,
                                                        const float* __restrict__ bias,
                                                        ushort* __restrict__ Hi,
                                                        ushort* __restrict__ Lo) {
    int wid = threadIdx.x >> 6;
    int lane = threadIdx.x & 63;
    int node = blockIdx.x * 4 + wid;
    if (node >= N_NODES) return;

    int s0 = row_ptr[node];
    int s1 = row_ptr[node + 1];

    float ax = 0.f, ay = 0.f;
    int e = s0;
    for (; e + 3 < s1; e += 4) {
        int2 e0 = csr[e + 0];
        int2 e1 = csr[e + 1];
        int2 e2 = csr[e + 2];
        int2 e3 = csr[e + 3];
        float2 v0 = *(const float2*)&g[(size_t)e0.x * HID_C + lane * 2];
        float2 v1 = *(const float2*)&g[(size_t)e1.x * HID_C + lane * 2];
        float2 v2 = *(const float2*)&g[(size_t)e2.x * HID_C + lane * 2];
        float2 v3 = *(const float2*)&g[(size_t)e3.x * HID_C + lane * 2];
        float w0 = __int_as_float(e0.y), w1 = __int_as_float(e1.y);
        float w2 = __int_as_float(e2.y), w3 = __int_as_float(e3.y);
        ax += w0 * v0.x + w1 * v1.x + w2 * v2.x + w3 * v3.x;
        ay += w0 * v0.y + w1 * v1.y + w2 * v2.y + w3 * v3.y;
    }
    for (; e < s1; e++) {
        int2 e0 = csr[e];
        float w0 = __int_as_float(e0.y);
        float2 v0 = *(const float2*)&g[(size_t)e0.x * HID_C + lane * 2];
        ax += w0 * v0.x;
        ay += w0 * v0.y;
    }
    float2 bb = *(const float2*)&bias[lane * 2];
    float ox = fmaxf(ax + bb.x, 0.f);
    float oy = fmaxf(ay + bb.y, 0.f);
    ushort2 ho, lo2;
    ho.x = f2bf(ox);
    lo2.x = f2bf(ox - bf2f(ho.x));
    ho.y = f2bf(oy);
    lo2.y = f2bf(oy - bf2f(ho.y));
    *(ushort2*)&Hi[(size_t)node * HID_C + lane * 2] = ho;
    *(ushort2*)&Lo[(size_t)node * HID_C + lane * 2] = lo2;
}

// ---------------------------------------------------------------------------
// Launch
// ---------------------------------------------------------------------------

extern "C" void kernel_launch(void* const* d_in, const int* in_sizes, int n_in,
                              void* d_out, int out_size, void* d_ws, size_t ws_size,
                              hipStream_t stream) {
    const float* x       = (const float*)d_in[0];
    const int*   eidx    = (const int*)d_in[1];
    const float* proj_W  = (const float*)d_in[2];
    const float* proj_b  = (const float*)d_in[3];
    const float* conv_W0 = (const float*)d_in[4];
    const float* conv_b0 = (const float*)d_in[5];
    const float* conv_W1 = (const float*)d_in[6];
    const float* conv_b1 = (const float*)d_in[7];
    const float* conv_W2 = (const float*)d_in[8];
    const float* conv_b2 = (const float*)d_in[9];
    const float* out_W   = (const float*)d_in[10];
    const float* out_b   = (const float*)d_in[11];
    float* out = (float*)d_out;

    const int* src = eidx;
    const int* dst = eidx + N_EDGES;

    char* ws = (char*)d_ws;
    size_t off = 0;
    auto carve = [&](size_t bytes) {
        void* p = ws + off;
        off += (bytes + 255) & ~(size_t)255;
        return p;
    };
    int*   degi     = (int*)carve(N_NODES * sizeof(int));
    int*   row_ptr  = (int*)carve((N_NODES + 1) * sizeof(int));
    int*   cursor   = (int*)carve(N_NODES * sizeof(int));
    int2*  csr      = (int2*)carve((size_t)(N_EDGES + N_NODES) * sizeof(int2));
    float* dis      = (float*)carve(N_NODES * sizeof(float));
    int*   partials = (int*)carve(NB_SCAN * sizeof(int));
    int*   poff     = (int*)carve(NB_SCAN * sizeof(int));
    // packed weights (hi/lo): proj 256x128, conv 3x 128x128, out 128x64
    ushort* projPh = (ushort*)carve((size_t)IN_C * HID_C * sizeof(ushort));
    ushort* projPl = (ushort*)carve((size_t)IN_C * HID_C * sizeof(ushort));
    ushort* convPh[3], *convPl[3];
    for (int l = 0; l < 3; l++) {
        convPh[l] = (ushort*)carve((size_t)HID_C * HID_C * sizeof(ushort));
        convPl[l] = (ushort*)carve((size_t)HID_C * HID_C * sizeof(ushort));
    }
    ushort* outPh = (ushort*)carve((size_t)HID_C * OUT_C * sizeof(ushort));
    ushort* outPl = (ushort*)carve((size_t)HID_C * OUT_C * sizeof(ushort));
    // activations
    ushort* hHi = (ushort*)carve((size_t)N_NODES * HID_C * sizeof(ushort));
    ushort* hLo = (ushort*)carve((size_t)N_NODES * HID_C * sizeof(ushort));
    float*  g   = (float*)carve((size_t)N_NODES * HID_C * sizeof(float));

    // Graph preprocessing
    init_deg_kernel<<<NB_SCAN, 256, 0, stream>>>(degi);
    count_deg_kernel<<<(N_EDGES + 255) / 256, 256, 0, stream>>>(dst, degi);
    deg_partial_kernel<<<NB_SCAN, 256, 0, stream>>>(degi, partials);
    scan_partials_kernel<<<1, 256, 0, stream>>>(partials, poff, row_ptr);
    scan_final_kernel<<<NB_SCAN, 256, 0, stream>>>(degi, poff, row_ptr, cursor, dis);
    scatter_kernel<<<(N_EDGES + N_NODES + 255) / 256, 256, 0, stream>>>(
        src, dst, dis, cursor, csr);

    // Weight packing
    pack_w_kernel<<<(IN_C / 32) * (HID_C / 16), 64, 0, stream>>>(proj_W, projPh, projPl, IN_C, HID_C);
    pack_w_kernel<<<(HID_C / 32) * (HID_C / 16), 64, 0, stream>>>(conv_W0, convPh[0], convPl[0], HID_C, HID_C);
    pack_w_kernel<<<(HID_C / 32) * (HID_C / 16), 64, 0, stream>>>(conv_W1, convPh[1], convPl[1], HID_C, HID_C);
    pack_w_kernel<<<(HID_C / 32) * (HID_C / 16), 64, 0, stream>>>(conv_W2, convPh[2], convPl[2], HID_C, HID_C);
    pack_w_kernel<<<(HID_C / 32) * (OUT_C / 16), 64, 0, stream>>>(out_W, outPh, outPl, HID_C, OUT_C);

    const int gemm_grid = (N_NODES + 127) / 128;  // 391

    // Projection: h = x @ proj_W + proj_b  -> hi/lo
    gemm_mfma_kernel<IN_C, HID_C, 1, true><<<gemm_grid, 256, 0, stream>>>(
        x, nullptr, nullptr, projPh, projPl, proj_b, nullptr, hHi, hLo, N_NODES);

    // 3 GCN layers
    ushort* Wh_[3] = {convPh[0], convPh[1], convPh[2]};
    ushort* Wl_[3] = {convPl[0], convPl[1], convPl[2]};
    const float* bs_[3] = {conv_b0, conv_b1, conv_b2};
    for (int l = 0; l < 3; l++) {
        gemm_mfma_kernel<HID_C, HID_C, 2, false><<<gemm_grid, 256, 0, stream>>>(
            nullptr, hHi, hLo, Wh_[l], Wl_[l], nullptr, g, nullptr, nullptr, N_NODES);
        aggregate_kernel<<<(N_NODES + 3) / 4, 256, 0, stream>>>(
            g, row_ptr, csr, bs_[l], hHi, hLo);
    }

    // Output: out = h @ out_W + out_b (fp32)
    gemm_mfma_kernel<HID_C, OUT_C, 0, false><<<gemm_grid, 256, 0, stream>>>(
        nullptr, hHi, hLo, outPh, outPl, out_b, out, nullptr, nullptr, N_NODES);
}